// Round 2
// baseline (286.487 us; speedup 1.0000x reference)
//
#include <hip/hip_runtime.h>
#include <math.h>

#define T_LEN 2097152
#define K 8
#define D 4
#define CHUNK 8
#define NTH (T_LEN / CHUNK)   // 262144 threads
#define TPB 256
#define NBLK (NTH / TPB)      // 1024 blocks -> 4 blocks/CU resident

// ws layout (as float*):
// [0..63]    Tr (row-stochastic transition probs)
// [64..71]   a[k]   (emission const, log2-scaled)
// [72..103]  b[k][d] (mu*ivar, log2-scaled)
// [104..135] c[k][d] (-0.5*ivar, log2-scaled)
// [136..143] alpha0[k]
// [256 .. 256+NBLK*64)          per-block transfer matrices (bp)
// ints at 256+NBLK*64 (=65792): NBLK shifts (bs)
// int at 66816:                 completion counter (zeroed via hipMemsetAsync)

__device__ __forceinline__ void mat_combine(const float L[K][K], const float R[K][K], float C[K][K]) {
#pragma unroll
    for (int i = 0; i < K; ++i) {
        float q[K];
#pragma unroll
        for (int j = 0; j < K; ++j) q[j] = L[i][0] * R[0][j];
#pragma unroll
        for (int k = 1; k < K; ++k)
#pragma unroll
            for (int j = 0; j < K; ++j) q[j] = fmaf(L[i][k], R[k][j], q[j]);
#pragma unroll
        for (int j = 0; j < K; ++j) C[i][j] = q[j];
    }
}

__device__ __forceinline__ void mat_copy(float Dst[K][K], const float S[K][K]) {
#pragma unroll
    for (int i = 0; i < K; ++i)
#pragma unroll
        for (int j = 0; j < K; ++j) Dst[i][j] = S[i][j];
}

// exact power-of-two renorm; invariant: true = P * 2^shift
__device__ __forceinline__ void renorm_mat(float P[K][K], int& shift) {
    float mx = 0.f;
#pragma unroll
    for (int i = 0; i < K; ++i)
#pragma unroll
        for (int j = 0; j < K; ++j) mx = fmaxf(mx, P[i][j]);
    int ex = (__float_as_int(mx) >> 23) & 255;
    float scale = __int_as_float((254 - ex) << 23); // 2^(127-ex)
    shift += ex - 127;
#pragma unroll
    for (int i = 0; i < K; ++i)
#pragma unroll
        for (int j = 0; j < K; ++j) P[i][j] *= scale;
}

// in-block combine over 256 time-ordered per-thread matrices (8 LDS levels);
// result lands in thread TPB-1.
__device__ __forceinline__ void block_tree(float P[K][K], int& shift, float* lm, int* lsh) {
    const int t = threadIdx.x;
#pragma unroll 1
    for (int lvl = 1; lvl <= 8; ++lvl) {
        const int span = 1 << (lvl - 1);
        bool holder = ((t & (span - 1)) == (span - 1));
        bool sender = holder && (((t >> (lvl - 1)) & 1) == 0);
        bool receiver = holder && (((t >> (lvl - 1)) & 1) == 1);
        int slot = t >> lvl;
        if (sender) {
#pragma unroll
            for (int i = 0; i < K; ++i)
#pragma unroll
                for (int j = 0; j < K; ++j) lm[slot * 64 + i * 8 + j] = P[i][j];
            lsh[slot] = shift;
        }
        __syncthreads();
        if (receiver) {
            float L[K][K];
#pragma unroll
            for (int i = 0; i < K; ++i)
#pragma unroll
                for (int k = 0; k < K; ++k) L[i][k] = lm[slot * 64 + i * 8 + k];
            float C[K][K];
            mat_combine(L, P, C); // L is earlier in time
            mat_copy(P, C);
            shift += lsh[slot];
            renorm_mat(P, shift);
        }
        __syncthreads();
    }
}

// 64-thread parallel setup
__global__ void hmm_setup(const float* __restrict__ x,
                          const float* __restrict__ ut,
                          const float* __restrict__ up,
                          const float* __restrict__ mn,
                          const float* __restrict__ lsd,
                          float* __restrict__ ws) {
    const int lane = threadIdx.x; // 64 threads, 1 wave
    const float L2PI = 1.83787706640934548356f;
    const float LOG2E = 1.44269504088896340736f;

    // transition softmax: lane -> (i = lane>>3, j = lane&7), row groups of 8
    float v = ut[lane];
    float m = v;
    m = fmaxf(m, __shfl_xor(m, 1));
    m = fmaxf(m, __shfl_xor(m, 2));
    m = fmaxf(m, __shfl_xor(m, 4));
    float e = expf(v - m);
    float s = e;
    s += __shfl_xor(s, 1); s += __shfl_xor(s, 2); s += __shfl_xor(s, 4);
    ws[lane] = e / s;

    // pi softmax (redundant on all lanes; each 8-lane group reduces the same data)
    float pv = up[lane & 7];
    float pm = pv;
    pm = fmaxf(pm, __shfl_xor(pm, 1));
    pm = fmaxf(pm, __shfl_xor(pm, 2));
    pm = fmaxf(pm, __shfl_xor(pm, 4));
    float pe = expf(pv - pm);
    float ps = pe;
    ps += __shfl_xor(ps, 1); ps += __shfl_xor(ps, 2); ps += __shfl_xor(ps, 4);
    float pival = pe / ps; // pi[lane & 7]

    // emission coefs: (k = (lane&31)>>2, d = lane&3); lanes 32..63 mirror 0..31
    int k = (lane & 31) >> 2, d = lane & 3;
    float lv = lsd[k * D + d];
    float mu = mn[k * D + d];
    float iv = expf(-2.f * lv);
    float bn = mu * iv;
    float cn = -0.5f * iv;
    float aterm = -0.5f * L2PI - lv - 0.5f * mu * mu * iv;
    float ak = aterm;
    ak += __shfl_xor(ak, 1); ak += __shfl_xor(ak, 2); // sum over d within group of 4
    if (lane < 32) {
        ws[72 + lane]  = bn * LOG2E;
        ws[104 + lane] = cn * LOG2E;
        if (d == 0) ws[64 + k] = ak * LOG2E;
    }

    // alpha0[k] = pi[k] * exp(em(t=0)) in natural log domain
    float xd = x[d];
    float part = (cn * xd + bn) * xd + aterm;
    part += __shfl_xor(part, 1); part += __shfl_xor(part, 2); // em_k on all lanes of group
    float pik = __shfl(pival, k);
    if (lane < 32 && d == 0) ws[136 + k] = pik * expf(part);
}

__global__ __launch_bounds__(TPB, 4) void hmm_fused(const float* __restrict__ x,
                                                    const float* __restrict__ cst,
                                                    float* __restrict__ bp,
                                                    int* __restrict__ bs,
                                                    int* __restrict__ counter,
                                                    float* __restrict__ out) {
    __shared__ float lm[128 * 64];
    __shared__ int lsh[128];
    __shared__ int lastFlag;
    const int tid = blockIdx.x * TPB + threadIdx.x;

    // uniform constants -> scalar loads / SGPRs
    float Tr[K][K];
#pragma unroll
    for (int i = 0; i < K; ++i)
#pragma unroll
        for (int j = 0; j < K; ++j) Tr[i][j] = cst[i * K + j];
    float ca[K], cb[K][D], cc[K][D];
#pragma unroll
    for (int k = 0; k < K; ++k) {
        ca[k] = cst[64 + k];
#pragma unroll
        for (int d = 0; d < D; ++d) {
            cb[k][d] = cst[72 + k * D + d];
            cc[k][d] = cst[104 + k * D + d];
        }
    }

    const float4* xv = reinterpret_cast<const float4*>(x) + (size_t)tid * CHUNK;

    float P[K][K];
    int shift = 0;
    if (tid == 0) {
#pragma unroll
        for (int i = 0; i < K; ++i)
#pragma unroll
            for (int j = 0; j < K; ++j) P[i][j] = (i == j) ? cst[136 + i] : 0.0f;
    } else {
        float4 x0 = xv[0];
        float e[K];
#pragma unroll
        for (int j = 0; j < K; ++j) {
            float em = ca[j];
            em = fmaf(fmaf(cc[j][0], x0.x, cb[j][0]), x0.x, em);
            em = fmaf(fmaf(cc[j][1], x0.y, cb[j][1]), x0.y, em);
            em = fmaf(fmaf(cc[j][2], x0.z, cb[j][2]), x0.z, em);
            em = fmaf(fmaf(cc[j][3], x0.w, cb[j][3]), x0.w, em);
            e[j] = exp2f(em);
        }
#pragma unroll
        for (int i = 0; i < K; ++i)
#pragma unroll
            for (int j = 0; j < K; ++j) P[i][j] = Tr[i][j] * e[j];
    }

    // scan: P <- (P*Tr) .col e_t ; pow2 renorm every 2nd step, folded into next e
    float fcarry = 0.0f;
    int icarry = 0;
    float4 xnext = xv[1];
#pragma unroll 1
    for (int t = 1; t < CHUNK; ++t) {
        float4 xt = xnext;
        int tn = (t + 1 < CHUNK) ? (t + 1) : t;
        xnext = xv[tn];
        float e[K];
#pragma unroll
        for (int j = 0; j < K; ++j) {
            float em = ca[j];
            em = fmaf(fmaf(cc[j][0], xt.x, cb[j][0]), xt.x, em);
            em = fmaf(fmaf(cc[j][1], xt.y, cb[j][1]), xt.y, em);
            em = fmaf(fmaf(cc[j][2], xt.z, cb[j][2]), xt.z, em);
            em = fmaf(fmaf(cc[j][3], xt.w, cb[j][3]), xt.w, em);
            e[j] = exp2f(em + fcarry);
        }
        shift -= icarry;
#pragma unroll
        for (int i = 0; i < K; ++i) {
            float q[K];
#pragma unroll
            for (int j = 0; j < K; ++j) q[j] = P[i][0] * Tr[0][j];
#pragma unroll
            for (int k = 1; k < K; ++k)
#pragma unroll
                for (int j = 0; j < K; ++j) q[j] = fmaf(P[i][k], Tr[k][j], q[j]);
#pragma unroll
            for (int j = 0; j < K; ++j) P[i][j] = q[j] * e[j];
        }
        if ((t & 1) == 0) { // uniform branch: renorm every 2nd step
            float mx = 0.f;
#pragma unroll
            for (int i = 0; i < K; ++i)
#pragma unroll
                for (int j = 0; j < K; ++j) mx = fmaxf(mx, P[i][j]);
            int ex = (__float_as_int(mx) >> 23) & 255;
            icarry = 127 - ex;
            fcarry = (float)icarry;
        } else {
            icarry = 0;
            fcarry = 0.0f;
        }
    }
    renorm_mat(P, shift);

    block_tree(P, shift, lm, lsh);

    // write block product; last block to finish does the final reduction
    if (threadIdx.x == TPB - 1) {
        float* o = bp + (size_t)blockIdx.x * 64;
#pragma unroll
        for (int i = 0; i < K; ++i)
#pragma unroll
            for (int j = 0; j < K; ++j) o[i * 8 + j] = P[i][j];
        bs[blockIdx.x] = shift;
        __threadfence(); // release: make bp/bs visible device-wide
        int old = atomicAdd(counter, 1);
        lastFlag = (old == NBLK - 1) ? 1 : 0;
    }
    __syncthreads();
    if (!lastFlag) return;
    __threadfence(); // acquire side

    // final phase (one block, 256 threads): 4 serial combines each, then tree
    {
        const int base = threadIdx.x * 4;
        const float* p0 = bp + (size_t)base * 64;
#pragma unroll
        for (int i = 0; i < K; ++i)
#pragma unroll
            for (int j = 0; j < K; ++j) P[i][j] = p0[i * 8 + j];
        shift = bs[base];
#pragma unroll 1
        for (int m = 1; m < 4; ++m) {
            const float* rp = bp + (size_t)(base + m) * 64;
            float R[K][K];
#pragma unroll
            for (int i = 0; i < K; ++i)
#pragma unroll
                for (int j = 0; j < K; ++j) R[i][j] = rp[i * 8 + j];
            float C[K][K];
            mat_combine(P, R, C);
            mat_copy(P, C);
            shift += bs[base + m];
            renorm_mat(P, shift);
        }
        block_tree(P, shift, lm, lsh);
        if (threadIdx.x == TPB - 1) {
            double s = 0.0;
#pragma unroll
            for (int i = 0; i < K; ++i)
#pragma unroll
                for (int j = 0; j < K; ++j) s += (double)P[i][j];
            out[0] = (float)(log(s) + (double)shift * 0.69314718055994530942);
        }
    }
}

extern "C" void kernel_launch(void* const* d_in, const int* in_sizes, int n_in,
                              void* d_out, int out_size, void* d_ws, size_t ws_size,
                              hipStream_t stream) {
    (void)in_sizes; (void)n_in; (void)out_size; (void)ws_size;
    const float* x  = (const float*)d_in[0];
    const float* ut = (const float*)d_in[1];
    const float* up = (const float*)d_in[2];
    const float* mn = (const float*)d_in[3];
    const float* ls = (const float*)d_in[4];
    float* ws  = (float*)d_ws;
    float* out = (float*)d_out;
    float* bp  = ws + 256;
    int* bs    = (int*)(ws + 256 + (size_t)NBLK * 64);
    int* cnt   = (int*)(ws + 256 + (size_t)NBLK * 64 + NBLK);

    hmm_setup<<<1, 64, 0, stream>>>(x, ut, up, mn, ls, ws);
    hipMemsetAsync((void*)cnt, 0, sizeof(int), stream);
    hmm_fused<<<NBLK, TPB, 0, stream>>>(x, ws, bp, bs, cnt, out);
}

// Round 5
// 180.275 us; speedup vs baseline: 1.5892x; 1.5892x over previous
//
#include <hip/hip_runtime.h>
#include <math.h>

#define T_LEN 2097152
#define K 8
#define D 4
#define CHUNK 8
#define NTH (T_LEN / CHUNK)   // 262144 threads
#define TPB 256
#define NBLK (NTH / TPB)      // 1024 blocks -> 4 blocks/CU resident

// ws layout (as float*):
// [0..63]    Tr (row-stochastic transition probs)
// [64..71]   a[k]   (emission const, log2-scaled)
// [72..103]  b[k][d] (mu*ivar, log2-scaled)
// [104..135] c[k][d] (-0.5*ivar, log2-scaled)
// [136..143] alpha0[k]
// [256 .. 256+NBLK*64)          per-block transfer matrices (bp)
// ints at 256+NBLK*64:          NBLK shifts (bs)

__device__ __forceinline__ void mat_combine(const float L[K][K], const float R[K][K], float C[K][K]) {
#pragma unroll
    for (int i = 0; i < K; ++i) {
        float q[K];
#pragma unroll
        for (int j = 0; j < K; ++j) q[j] = L[i][0] * R[0][j];
#pragma unroll
        for (int k = 1; k < K; ++k)
#pragma unroll
            for (int j = 0; j < K; ++j) q[j] = fmaf(L[i][k], R[k][j], q[j]);
#pragma unroll
        for (int j = 0; j < K; ++j) C[i][j] = q[j];
    }
}

__device__ __forceinline__ void mat_copy(float Dst[K][K], const float S[K][K]) {
#pragma unroll
    for (int i = 0; i < K; ++i)
#pragma unroll
        for (int j = 0; j < K; ++j) Dst[i][j] = S[i][j];
}

// exact power-of-two renorm; invariant: true = P * 2^shift
__device__ __forceinline__ void renorm_mat(float P[K][K], int& shift) {
    float mx = 0.f;
#pragma unroll
    for (int i = 0; i < K; ++i)
#pragma unroll
        for (int j = 0; j < K; ++j) mx = fmaxf(mx, P[i][j]);
    int ex = (__float_as_int(mx) >> 23) & 255;
    float scale = __int_as_float((254 - ex) << 23); // 2^(127-ex)
    shift += ex - 127;
#pragma unroll
    for (int i = 0; i < K; ++i)
#pragma unroll
        for (int j = 0; j < K; ++j) P[i][j] *= scale;
}

// in-block combine over 256 time-ordered per-thread matrices (8 LDS levels);
// result lands in thread TPB-1.
__device__ __forceinline__ void block_tree(float P[K][K], int& shift, float* lm, int* lsh) {
    const int t = threadIdx.x;
#pragma unroll 1
    for (int lvl = 1; lvl <= 8; ++lvl) {
        const int span = 1 << (lvl - 1);
        bool holder = ((t & (span - 1)) == (span - 1));
        bool sender = holder && (((t >> (lvl - 1)) & 1) == 0);
        bool receiver = holder && (((t >> (lvl - 1)) & 1) == 1);
        int slot = t >> lvl;
        if (sender) {
#pragma unroll
            for (int i = 0; i < K; ++i)
#pragma unroll
                for (int j = 0; j < K; ++j) lm[slot * 64 + i * 8 + j] = P[i][j];
            lsh[slot] = shift;
        }
        __syncthreads();
        if (receiver) {
            float L[K][K];
#pragma unroll
            for (int i = 0; i < K; ++i)
#pragma unroll
                for (int k = 0; k < K; ++k) L[i][k] = lm[slot * 64 + i * 8 + k];
            float C[K][K];
            mat_combine(L, P, C); // L is earlier in time
            mat_copy(P, C);
            shift += lsh[slot];
            renorm_mat(P, shift);
        }
        __syncthreads();
    }
}

// 64-thread parallel setup
__global__ void hmm_setup(const float* __restrict__ x,
                          const float* __restrict__ ut,
                          const float* __restrict__ up,
                          const float* __restrict__ mn,
                          const float* __restrict__ lsd,
                          float* __restrict__ ws) {
    const int lane = threadIdx.x; // 64 threads, 1 wave
    const float L2PI = 1.83787706640934548356f;
    const float LOG2E = 1.44269504088896340736f;

    // transition softmax: lane -> (i = lane>>3, j = lane&7)
    float v = ut[lane];
    float m = v;
    m = fmaxf(m, __shfl_xor(m, 1));
    m = fmaxf(m, __shfl_xor(m, 2));
    m = fmaxf(m, __shfl_xor(m, 4));
    float e = expf(v - m);
    float s = e;
    s += __shfl_xor(s, 1); s += __shfl_xor(s, 2); s += __shfl_xor(s, 4);
    ws[lane] = e / s;

    // pi softmax (each 8-lane group reduces the same data)
    float pv = up[lane & 7];
    float pm = pv;
    pm = fmaxf(pm, __shfl_xor(pm, 1));
    pm = fmaxf(pm, __shfl_xor(pm, 2));
    pm = fmaxf(pm, __shfl_xor(pm, 4));
    float pe = expf(pv - pm);
    float ps = pe;
    ps += __shfl_xor(ps, 1); ps += __shfl_xor(ps, 2); ps += __shfl_xor(ps, 4);
    float pival = pe / ps; // pi[lane & 7]

    // emission coefs: (k = (lane&31)>>2, d = lane&3); lanes 32..63 mirror 0..31
    int k = (lane & 31) >> 2, d = lane & 3;
    float lv = lsd[k * D + d];
    float mu = mn[k * D + d];
    float iv = expf(-2.f * lv);
    float bn = mu * iv;
    float cn = -0.5f * iv;
    float aterm = -0.5f * L2PI - lv - 0.5f * mu * mu * iv;
    float ak = aterm;
    ak += __shfl_xor(ak, 1); ak += __shfl_xor(ak, 2); // sum over d in group of 4
    if (lane < 32) {
        ws[72 + lane]  = bn * LOG2E;
        ws[104 + lane] = cn * LOG2E;
        if (d == 0) ws[64 + k] = ak * LOG2E;
    }

    // alpha0[k] = pi[k] * exp(em(t=0)) in natural log domain
    float xd = x[d];
    float part = (cn * xd + bn) * xd + aterm;
    part += __shfl_xor(part, 1); part += __shfl_xor(part, 2);
    float pik = __shfl(pival, k);
    if (lane < 32 && d == 0) ws[136 + k] = pik * expf(part);
}

__global__ __launch_bounds__(TPB) void hmm_main(const float* __restrict__ x,
                                                const float* __restrict__ cst,
                                                float* __restrict__ bp,
                                                int* __restrict__ bs) {
    __shared__ float lm[128 * 64];
    __shared__ int lsh[128];
    const int tid = blockIdx.x * TPB + threadIdx.x;

    // uniform constants -> scalar loads / SGPRs
    float Tr[K][K];
#pragma unroll
    for (int i = 0; i < K; ++i)
#pragma unroll
        for (int j = 0; j < K; ++j) Tr[i][j] = cst[i * K + j];
    float ca[K], cb[K][D], cc[K][D];
#pragma unroll
    for (int k = 0; k < K; ++k) {
        ca[k] = cst[64 + k];
#pragma unroll
        for (int d = 0; d < D; ++d) {
            cb[k][d] = cst[72 + k * D + d];
            cc[k][d] = cst[104 + k * D + d];
        }
    }

    const float4* xv = reinterpret_cast<const float4*>(x) + (size_t)tid * CHUNK;

    float P[K][K];
    int shift = 0;
    if (tid == 0) {
#pragma unroll
        for (int i = 0; i < K; ++i)
#pragma unroll
            for (int j = 0; j < K; ++j) P[i][j] = (i == j) ? cst[136 + i] : 0.0f;
    } else {
        float4 x0 = xv[0];
        float e[K];
#pragma unroll
        for (int j = 0; j < K; ++j) {
            float em = ca[j];
            em = fmaf(fmaf(cc[j][0], x0.x, cb[j][0]), x0.x, em);
            em = fmaf(fmaf(cc[j][1], x0.y, cb[j][1]), x0.y, em);
            em = fmaf(fmaf(cc[j][2], x0.z, cb[j][2]), x0.z, em);
            em = fmaf(fmaf(cc[j][3], x0.w, cb[j][3]), x0.w, em);
            e[j] = exp2f(em);
        }
#pragma unroll
        for (int i = 0; i < K; ++i)
#pragma unroll
            for (int j = 0; j < K; ++j) P[i][j] = Tr[i][j] * e[j];
    }

    // scan: P <- (P*Tr) .col e_t ; pow2 renorm every 2nd step, folded into next e
    float fcarry = 0.0f;
    int icarry = 0;
    float4 xnext = xv[1];
#pragma unroll 1
    for (int t = 1; t < CHUNK; ++t) {
        float4 xt = xnext;
        int tn = (t + 1 < CHUNK) ? (t + 1) : t;
        xnext = xv[tn];
        float e[K];
#pragma unroll
        for (int j = 0; j < K; ++j) {
            float em = ca[j];
            em = fmaf(fmaf(cc[j][0], xt.x, cb[j][0]), xt.x, em);
            em = fmaf(fmaf(cc[j][1], xt.y, cb[j][1]), xt.y, em);
            em = fmaf(fmaf(cc[j][2], xt.z, cb[j][2]), xt.z, em);
            em = fmaf(fmaf(cc[j][3], xt.w, cb[j][3]), xt.w, em);
            e[j] = exp2f(em + fcarry);
        }
        shift -= icarry;
#pragma unroll
        for (int i = 0; i < K; ++i) {
            float q[K];
#pragma unroll
            for (int j = 0; j < K; ++j) q[j] = P[i][0] * Tr[0][j];
#pragma unroll
            for (int k = 1; k < K; ++k)
#pragma unroll
                for (int j = 0; j < K; ++j) q[j] = fmaf(P[i][k], Tr[k][j], q[j]);
#pragma unroll
            for (int j = 0; j < K; ++j) P[i][j] = q[j] * e[j];
        }
        if ((t & 1) == 0) { // uniform: renorm every 2nd step
            float mx = 0.f;
#pragma unroll
            for (int i = 0; i < K; ++i)
#pragma unroll
                for (int j = 0; j < K; ++j) mx = fmaxf(mx, P[i][j]);
            int ex = (__float_as_int(mx) >> 23) & 255;
            icarry = 127 - ex;
            fcarry = (float)icarry;
        } else {
            icarry = 0;
            fcarry = 0.0f;
        }
    }
    renorm_mat(P, shift);

    block_tree(P, shift, lm, lsh);

    if (threadIdx.x == TPB - 1) {
        float* o = bp + (size_t)blockIdx.x * 64;
#pragma unroll
        for (int i = 0; i < K; ++i)
#pragma unroll
            for (int j = 0; j < K; ++j) o[i * 8 + j] = P[i][j];
        bs[blockIdx.x] = shift;
    }
}

// 256-thread final: 4 serial combines per thread, then the 8-level tree
__global__ void hmm_final(const float* __restrict__ bp,
                          const int* __restrict__ bs,
                          float* __restrict__ out) {
    __shared__ float lm[128 * 64];
    __shared__ int lsh[128];
    const int base = threadIdx.x * 4;

    float P[K][K];
    const float* p0 = bp + (size_t)base * 64;
#pragma unroll
    for (int i = 0; i < K; ++i)
#pragma unroll
        for (int j = 0; j < K; ++j) P[i][j] = p0[i * 8 + j];
    int shift = bs[base];
#pragma unroll 1
    for (int m = 1; m < 4; ++m) {
        const float* rp = bp + (size_t)(base + m) * 64;
        float R[K][K];
#pragma unroll
        for (int i = 0; i < K; ++i)
#pragma unroll
            for (int j = 0; j < K; ++j) R[i][j] = rp[i * 8 + j];
        float C[K][K];
        mat_combine(P, R, C);
        mat_copy(P, C);
        shift += bs[base + m];
        renorm_mat(P, shift);
    }

    block_tree(P, shift, lm, lsh);

    if (threadIdx.x == TPB - 1) {
        double s = 0.0;
#pragma unroll
        for (int i = 0; i < K; ++i)
#pragma unroll
            for (int j = 0; j < K; ++j) s += (double)P[i][j];
        out[0] = (float)(log(s) + (double)shift * 0.69314718055994530942);
    }
}

extern "C" void kernel_launch(void* const* d_in, const int* in_sizes, int n_in,
                              void* d_out, int out_size, void* d_ws, size_t ws_size,
                              hipStream_t stream) {
    (void)in_sizes; (void)n_in; (void)out_size; (void)ws_size;
    const float* x  = (const float*)d_in[0];
    const float* ut = (const float*)d_in[1];
    const float* up = (const float*)d_in[2];
    const float* mn = (const float*)d_in[3];
    const float* ls = (const float*)d_in[4];
    float* ws  = (float*)d_ws;
    float* out = (float*)d_out;
    float* bp  = ws + 256;
    int* bs    = (int*)(ws + 256 + (size_t)NBLK * 64);

    hmm_setup<<<1, 64, 0, stream>>>(x, ut, up, mn, ls, ws);
    hmm_main<<<NBLK, TPB, 0, stream>>>(x, ws, bp, bs);
    hmm_final<<<1, TPB, 0, stream>>>(bp, bs, out);
}

// Round 7
// 160.182 us; speedup vs baseline: 1.7885x; 1.1254x over previous
//
#include <hip/hip_runtime.h>
#include <math.h>

#define T_LEN 2097152
#define K 8
#define D 4
#define CHUNK 16
#define TPB 128
#define NBLK (T_LEN / (CHUNK * TPB))  // 1024 blocks, 4/CU (LDS-bound)
#define MSTRIDE 65                    // LDS matrix stride (odd -> conflict-free)

// ws layout (as float*):
// [0..63]    Tr; [64..71] a[k]; [72..103] b[k][d]; [104..135] c[k][d]; [136..143] alpha0
// [256 .. 256+NBLK*64)  per-block transfer matrices (bp)
// ints at 256+NBLK*64:  NBLK shifts (bs); then 1 int completion counter

__device__ __forceinline__ void renorm_mat(float P[K][K], int& shift) {
    float mx = 0.f;
#pragma unroll
    for (int i = 0; i < K; ++i)
#pragma unroll
        for (int j = 0; j < K; ++j) mx = fmaxf(mx, P[i][j]);
    int ex = (__float_as_int(mx) >> 23) & 255;
    float scale = __int_as_float((254 - ex) << 23); // 2^(127-ex)
    shift += ex - 127;
#pragma unroll
    for (int i = 0; i < K; ++i)
#pragma unroll
        for (int j = 0; j < K; ++j) P[i][j] *= scale;
}

// C = L * R, streaming k: col of L (8) + row of R (8) live at a time
__device__ __forceinline__ void combine_stream(const float* __restrict__ Lp,
                                               const float* __restrict__ Rp,
                                               float C[K][K]) {
#pragma unroll
    for (int k = 0; k < K; ++k) {
        float Lc[K], Rr[K];
#pragma unroll
        for (int i = 0; i < K; ++i) Lc[i] = Lp[i * 8 + k];
#pragma unroll
        for (int j = 0; j < K; ++j) Rr[j] = Rp[k * 8 + j];
        if (k == 0) {
#pragma unroll
            for (int i = 0; i < K; ++i)
#pragma unroll
                for (int j = 0; j < K; ++j) C[i][j] = Lc[i] * Rr[j];
        } else {
#pragma unroll
            for (int i = 0; i < K; ++i)
#pragma unroll
                for (int j = 0; j < K; ++j) C[i][j] = fmaf(Lc[i], Rr[j], C[i][j]);
        }
    }
}

// packed tree over 128 time-ordered matrices in LDS (stride MSTRIDE);
// one combine per LANE, alternating wave per level. Result -> slot 0.
__device__ __forceinline__ void packed_tree(float* lm, int* lsh) {
    const int t = threadIdx.x;
    const int lane = t & 63, w = t >> 6;
#pragma unroll 1
    for (int lvl = 1; lvl <= 7; ++lvl) {
        const int c = 128 >> lvl;      // combines this level
        const int S = 1 << (lvl - 1);
        const int aw = (lvl & 1) ? 0 : 1;
        if (w == aw && lane < c) {
            const int li = (2 * lane) * S, ri = (2 * lane + 1) * S;
            float C[K][K];
            combine_stream(&lm[li * MSTRIDE], &lm[ri * MSTRIDE], C);
            int ns = lsh[li] + lsh[ri];
            renorm_mat(C, ns);
#pragma unroll
            for (int i = 0; i < K; ++i)
#pragma unroll
                for (int j = 0; j < K; ++j) lm[li * MSTRIDE + i * 8 + j] = C[i][j];
            lsh[li] = ns;
        }
        __syncthreads();
    }
}

// 64-thread parallel setup (keeps main's consts uniform->SGPR)
__global__ void hmm_setup(const float* __restrict__ x,
                          const float* __restrict__ ut,
                          const float* __restrict__ up,
                          const float* __restrict__ mn,
                          const float* __restrict__ lsd,
                          float* __restrict__ ws) {
    const int lane = threadIdx.x;
    const float L2PI = 1.83787706640934548356f;
    const float LOG2E = 1.44269504088896340736f;

    float v = ut[lane];
    float m = v;
    m = fmaxf(m, __shfl_xor(m, 1));
    m = fmaxf(m, __shfl_xor(m, 2));
    m = fmaxf(m, __shfl_xor(m, 4));
    float e = expf(v - m);
    float s = e;
    s += __shfl_xor(s, 1); s += __shfl_xor(s, 2); s += __shfl_xor(s, 4);
    ws[lane] = e / s;

    float pv = up[lane & 7];
    float pm = pv;
    pm = fmaxf(pm, __shfl_xor(pm, 1));
    pm = fmaxf(pm, __shfl_xor(pm, 2));
    pm = fmaxf(pm, __shfl_xor(pm, 4));
    float pe = expf(pv - pm);
    float ps = pe;
    ps += __shfl_xor(ps, 1); ps += __shfl_xor(ps, 2); ps += __shfl_xor(ps, 4);
    float pival = pe / ps;

    int k = (lane & 31) >> 2, d = lane & 3;
    float lv = lsd[k * D + d];
    float mu = mn[k * D + d];
    float iv = expf(-2.f * lv);
    float bn = mu * iv;
    float cn = -0.5f * iv;
    float aterm = -0.5f * L2PI - lv - 0.5f * mu * mu * iv;
    float ak = aterm;
    ak += __shfl_xor(ak, 1); ak += __shfl_xor(ak, 2);
    if (lane < 32) {
        ws[72 + lane]  = bn * LOG2E;
        ws[104 + lane] = cn * LOG2E;
        if (d == 0) ws[64 + k] = ak * LOG2E;
    }

    float xd = x[d];
    float part = (cn * xd + bn) * xd + aterm;
    part += __shfl_xor(part, 1); part += __shfl_xor(part, 2);
    float pik = __shfl(pival, k);
    if (lane < 32 && d == 0) ws[136 + k] = pik * expf(part);
}

__global__ __launch_bounds__(TPB) void hmm_main(const float* __restrict__ x,
                                                const float* __restrict__ cst,
                                                float* __restrict__ bp,
                                                int* __restrict__ bs,
                                                int* __restrict__ counter,
                                                float* __restrict__ out) {
    __shared__ float lm[128 * MSTRIDE];
    __shared__ int lsh[128];
    __shared__ int lastFlag;
    const int tid = blockIdx.x * TPB + threadIdx.x;

    // uniform constants -> scalar loads
    float Tr[K][K];
#pragma unroll
    for (int i = 0; i < K; ++i)
#pragma unroll
        for (int j = 0; j < K; ++j) Tr[i][j] = cst[i * K + j];
    float ca[K], cb[K][D], cc[K][D];
#pragma unroll
    for (int k = 0; k < K; ++k) {
        ca[k] = cst[64 + k];
#pragma unroll
        for (int d = 0; d < D; ++d) {
            cb[k][d] = cst[72 + k * D + d];
            cc[k][d] = cst[104 + k * D + d];
        }
    }

    const float4* xv = reinterpret_cast<const float4*>(x) + (size_t)tid * CHUNK;

    float P[K][K];
    int shift = 0;
    if (tid == 0) {
#pragma unroll
        for (int i = 0; i < K; ++i)
#pragma unroll
            for (int j = 0; j < K; ++j) P[i][j] = (i == j) ? cst[136 + i] : 0.0f;
    } else {
        float4 x0 = xv[0];
        float e[K];
#pragma unroll
        for (int j = 0; j < K; ++j) {
            float em = ca[j];
            em = fmaf(fmaf(cc[j][0], x0.x, cb[j][0]), x0.x, em);
            em = fmaf(fmaf(cc[j][1], x0.y, cb[j][1]), x0.y, em);
            em = fmaf(fmaf(cc[j][2], x0.z, cb[j][2]), x0.z, em);
            em = fmaf(fmaf(cc[j][3], x0.w, cb[j][3]), x0.w, em);
            e[j] = exp2f(em);
        }
#pragma unroll
        for (int i = 0; i < K; ++i)
#pragma unroll
            for (int j = 0; j < K; ++j) P[i][j] = Tr[i][j] * e[j];
    }

    // scan: P <- (P*Tr) .col e_t ; pow2 renorm every 2nd step folded into next e
    float fcarry = 0.0f;
    int icarry = 0;
    float4 xnext = xv[1];
#pragma unroll 1
    for (int t = 1; t < CHUNK; ++t) {
        float4 xt = xnext;
        int tn = (t + 1 < CHUNK) ? (t + 1) : t;
        xnext = xv[tn];
        float e[K];
#pragma unroll
        for (int j = 0; j < K; ++j) {
            float em = ca[j];
            em = fmaf(fmaf(cc[j][0], xt.x, cb[j][0]), xt.x, em);
            em = fmaf(fmaf(cc[j][1], xt.y, cb[j][1]), xt.y, em);
            em = fmaf(fmaf(cc[j][2], xt.z, cb[j][2]), xt.z, em);
            em = fmaf(fmaf(cc[j][3], xt.w, cb[j][3]), xt.w, em);
            e[j] = exp2f(em + fcarry);
        }
        shift -= icarry;
#pragma unroll
        for (int i = 0; i < K; ++i) {
            float q[K];
#pragma unroll
            for (int j = 0; j < K; ++j) q[j] = P[i][0] * Tr[0][j];
#pragma unroll
            for (int k = 1; k < K; ++k)
#pragma unroll
                for (int j = 0; j < K; ++j) q[j] = fmaf(P[i][k], Tr[k][j], q[j]);
#pragma unroll
            for (int j = 0; j < K; ++j) P[i][j] = q[j] * e[j];
        }
        if ((t & 1) == 0) {
            float mx = 0.f;
#pragma unroll
            for (int i = 0; i < K; ++i)
#pragma unroll
                for (int j = 0; j < K; ++j) mx = fmaxf(mx, P[i][j]);
            int ex = (__float_as_int(mx) >> 23) & 255;
            icarry = 127 - ex;
            fcarry = (float)icarry;
        } else {
            icarry = 0;
            fcarry = 0.0f;
        }
    }
    renorm_mat(P, shift);

    // dump chunk results to LDS, packed tree 128 -> 1
    {
        const int t = threadIdx.x;
#pragma unroll
        for (int i = 0; i < K; ++i)
#pragma unroll
            for (int j = 0; j < K; ++j) lm[t * MSTRIDE + i * 8 + j] = P[i][j];
        lsh[t] = shift;
    }
    __syncthreads();
    packed_tree(lm, lsh);

    // block product -> global; last block to finish reduces all blocks
    if (threadIdx.x == 0) {
        float4* o4 = reinterpret_cast<float4*>(bp + (size_t)blockIdx.x * 64);
        const float4* l4 = reinterpret_cast<const float4*>(lm);
#pragma unroll
        for (int q = 0; q < 16; ++q) o4[q] = l4[q];
        bs[blockIdx.x] = lsh[0];
        __threadfence(); // release
        int old = atomicAdd(counter, 1);
        lastFlag = (old == NBLK - 1) ? 1 : 0;
    }
    __syncthreads();
    if (!lastFlag) return;
    __threadfence(); // acquire

    // ---- final phase (last block only): 1024 mats -> 128 serial -> tree -> out
    {
        const int t = threadIdx.x;
        const int base = t * 8;
        float Pf[K][K];
        {
            const float4* p4 = reinterpret_cast<const float4*>(bp + (size_t)base * 64);
            float4* dst = reinterpret_cast<float4*>(&Pf[0][0]);
#pragma unroll
            for (int q = 0; q < 16; ++q) dst[q] = p4[q];
        }
        int sh = bs[base];
#pragma unroll 1
        for (int r = 1; r < 8; ++r) {
            const float* Rp = bp + (size_t)(base + r) * 64;
            float C[K][K];
            combine_stream(&Pf[0][0], Rp, C);
            sh += bs[base + r];
            renorm_mat(C, sh);
#pragma unroll
            for (int i = 0; i < K; ++i)
#pragma unroll
                for (int j = 0; j < K; ++j) Pf[i][j] = C[i][j];
        }
#pragma unroll
        for (int i = 0; i < K; ++i)
#pragma unroll
            for (int j = 0; j < K; ++j) lm[t * MSTRIDE + i * 8 + j] = Pf[i][j];
        lsh[t] = sh;
    }
    __syncthreads();
    packed_tree(lm, lsh);

    if (threadIdx.x == 0) {
        double s = 0.0;
#pragma unroll
        for (int i = 0; i < K; ++i)
#pragma unroll
            for (int j = 0; j < K; ++j) s += (double)lm[i * 8 + j];
        out[0] = (float)(log(s) + (double)lsh[0] * 0.69314718055994530942);
    }
}

extern "C" void kernel_launch(void* const* d_in, const int* in_sizes, int n_in,
                              void* d_out, int out_size, void* d_ws, size_t ws_size,
                              hipStream_t stream) {
    (void)in_sizes; (void)n_in; (void)out_size; (void)ws_size;
    const float* x  = (const float*)d_in[0];
    const float* ut = (const float*)d_in[1];
    const float* up = (const float*)d_in[2];
    const float* mn = (const float*)d_in[3];
    const float* ls = (const float*)d_in[4];
    float* ws  = (float*)d_ws;
    float* out = (float*)d_out;
    float* bp  = ws + 256;
    int* bs    = (int*)(ws + 256 + (size_t)NBLK * 64);
    int* cnt   = bs + NBLK;

    hmm_setup<<<1, 64, 0, stream>>>(x, ut, up, mn, ls, ws);
    hipMemsetAsync((void*)cnt, 0, sizeof(int), stream);
    hmm_main<<<NBLK, TPB, 0, stream>>>(x, ws, bp, bs, cnt, out);
}

// Round 8
// 152.720 us; speedup vs baseline: 1.8759x; 1.0489x over previous
//
#include <hip/hip_runtime.h>
#include <math.h>

#define T_LEN 2097152
#define K 8
#define D 4
#define CHUNK 8
#define TPB 256
#define NBLK (T_LEN / (CHUNK * TPB))  // 1024 blocks -> 4/CU (LDS-bound), 16 waves/CU
#define MSTRIDE 65                    // LDS matrix stride (floats)

// ws layout (as float*):
// [0..63] Tr; [64..71] a[k]; [72..103] b[k][d]; [104..135] c[k][d]; [136..143] alpha0
// [256 ..) per-block transfer matrices bp (NBLK*64 floats), then bs (NBLK ints)

__device__ __forceinline__ void renorm_mat(float P[K][K], int& shift) {
    float mx = 0.f;
#pragma unroll
    for (int i = 0; i < K; ++i)
#pragma unroll
        for (int j = 0; j < K; ++j) mx = fmaxf(mx, P[i][j]);
    int ex = (__float_as_int(mx) >> 23) & 255;
    float scale = __int_as_float((254 - ex) << 23); // 2^(127-ex)
    shift += ex - 127;
#pragma unroll
    for (int i = 0; i < K; ++i)
#pragma unroll
        for (int j = 0; j < K; ++j) P[i][j] *= scale;
}

__device__ __forceinline__ void mat_combine(const float L[K][K], const float R[K][K], float C[K][K]) {
#pragma unroll
    for (int i = 0; i < K; ++i) {
        float q[K];
#pragma unroll
        for (int j = 0; j < K; ++j) q[j] = L[i][0] * R[0][j];
#pragma unroll
        for (int k = 1; k < K; ++k)
#pragma unroll
            for (int j = 0; j < K; ++j) q[j] = fmaf(L[i][k], R[k][j], q[j]);
#pragma unroll
        for (int j = 0; j < K; ++j) C[i][j] = q[j];
    }
}

// C = L * R with both operands addressed through pointers (LDS or global)
__device__ __forceinline__ void combine_stream(const float* __restrict__ Lp,
                                               const float* __restrict__ Rp,
                                               float C[K][K]) {
#pragma unroll
    for (int k = 0; k < K; ++k) {
        float Lc[K], Rr[K];
#pragma unroll
        for (int i = 0; i < K; ++i) Lc[i] = Lp[i * 8 + k];
#pragma unroll
        for (int j = 0; j < K; ++j) Rr[j] = Rp[k * 8 + j];
        if (k == 0) {
#pragma unroll
            for (int i = 0; i < K; ++i)
#pragma unroll
                for (int j = 0; j < K; ++j) C[i][j] = Lc[i] * Rr[j];
        } else {
#pragma unroll
            for (int i = 0; i < K; ++i)
#pragma unroll
                for (int j = 0; j < K; ++j) C[i][j] = fmaf(Lc[i], Rr[j], C[i][j]);
        }
    }
}

// Hybrid tree over 256 time-ordered per-thread matrices.
// Level 1: masked pair-combine through 128 LDS slots (keeps LDS at 33.8KB).
// Levels 2..8: packed, one combine per lane. Result -> LDS slot 0 / lsh[0].
__device__ __forceinline__ void hybrid_tree(float P[K][K], int& shift, float* lm, int* lsh) {
    const int t = threadIdx.x;
    // level 1: even threads (earlier chunk) publish; odd threads combine L*own
    if ((t & 1) == 0) {
#pragma unroll
        for (int i = 0; i < K; ++i)
#pragma unroll
            for (int j = 0; j < K; ++j) lm[(t >> 1) * MSTRIDE + i * 8 + j] = P[i][j];
        lsh[t >> 1] = shift;
    }
    __syncthreads();
    if (t & 1) {
        float L[K][K];
#pragma unroll
        for (int i = 0; i < K; ++i)
#pragma unroll
            for (int k = 0; k < K; ++k) L[i][k] = lm[(t >> 1) * MSTRIDE + i * 8 + k];
        float C[K][K];
        mat_combine(L, P, C); // L earlier in time
        int ns = shift + lsh[t >> 1];
        renorm_mat(C, ns);
#pragma unroll
        for (int i = 0; i < K; ++i)
#pragma unroll
            for (int j = 0; j < K; ++j) lm[(t >> 1) * MSTRIDE + i * 8 + j] = C[i][j];
        lsh[t >> 1] = ns;
    }
    __syncthreads();
    // packed rounds over 128 slots
    const int lane = t & 63, w = t >> 6;
#pragma unroll 1
    for (int r = 1; r <= 7; ++r) {
        const int c = 64 >> (r - 1);
        const int S = 1 << (r - 1);
        const int aw = r & 1;
        if (w == aw && lane < c) {
            const int li = (2 * lane) * S, ri = li + S;
            float C[K][K];
            combine_stream(&lm[li * MSTRIDE], &lm[ri * MSTRIDE], C);
            int ns = lsh[li] + lsh[ri];
            renorm_mat(C, ns);
#pragma unroll
            for (int i = 0; i < K; ++i)
#pragma unroll
                for (int j = 0; j < K; ++j) lm[li * MSTRIDE + i * 8 + j] = C[i][j];
            lsh[li] = ns;
        }
        __syncthreads();
    }
}

// 64-thread parallel setup (keeps main's consts uniform -> SGPR)
__global__ void hmm_setup(const float* __restrict__ x,
                          const float* __restrict__ ut,
                          const float* __restrict__ up,
                          const float* __restrict__ mn,
                          const float* __restrict__ lsd,
                          float* __restrict__ ws) {
    const int lane = threadIdx.x;
    const float L2PI = 1.83787706640934548356f;
    const float LOG2E = 1.44269504088896340736f;

    float v = ut[lane];
    float m = v;
    m = fmaxf(m, __shfl_xor(m, 1));
    m = fmaxf(m, __shfl_xor(m, 2));
    m = fmaxf(m, __shfl_xor(m, 4));
    float e = expf(v - m);
    float s = e;
    s += __shfl_xor(s, 1); s += __shfl_xor(s, 2); s += __shfl_xor(s, 4);
    ws[lane] = e / s;

    float pv = up[lane & 7];
    float pm = pv;
    pm = fmaxf(pm, __shfl_xor(pm, 1));
    pm = fmaxf(pm, __shfl_xor(pm, 2));
    pm = fmaxf(pm, __shfl_xor(pm, 4));
    float pe = expf(pv - pm);
    float ps = pe;
    ps += __shfl_xor(ps, 1); ps += __shfl_xor(ps, 2); ps += __shfl_xor(ps, 4);
    float pival = pe / ps;

    int k = (lane & 31) >> 2, d = lane & 3;
    float lv = lsd[k * D + d];
    float mu = mn[k * D + d];
    float iv = expf(-2.f * lv);
    float bn = mu * iv;
    float cn = -0.5f * iv;
    float aterm = -0.5f * L2PI - lv - 0.5f * mu * mu * iv;
    float ak = aterm;
    ak += __shfl_xor(ak, 1); ak += __shfl_xor(ak, 2);
    if (lane < 32) {
        ws[72 + lane]  = bn * LOG2E;
        ws[104 + lane] = cn * LOG2E;
        if (d == 0) ws[64 + k] = ak * LOG2E;
    }

    float xd = x[d];
    float part = (cn * xd + bn) * xd + aterm;
    part += __shfl_xor(part, 1); part += __shfl_xor(part, 2);
    float pik = __shfl(pival, k);
    if (lane < 32 && d == 0) ws[136 + k] = pik * expf(part);
}

__global__ __launch_bounds__(TPB) void hmm_main(const float* __restrict__ x,
                                                const float* __restrict__ cst,
                                                float* __restrict__ bp,
                                                int* __restrict__ bs) {
    __shared__ float lm[128 * MSTRIDE];
    __shared__ int lsh[128];
    const int tid = blockIdx.x * TPB + threadIdx.x;

    float Tr[K][K];
#pragma unroll
    for (int i = 0; i < K; ++i)
#pragma unroll
        for (int j = 0; j < K; ++j) Tr[i][j] = cst[i * K + j];
    float ca[K], cb[K][D], cc[K][D];
#pragma unroll
    for (int k = 0; k < K; ++k) {
        ca[k] = cst[64 + k];
#pragma unroll
        for (int d = 0; d < D; ++d) {
            cb[k][d] = cst[72 + k * D + d];
            cc[k][d] = cst[104 + k * D + d];
        }
    }

    const float4* xv = reinterpret_cast<const float4*>(x) + (size_t)tid * CHUNK;

    float P[K][K];
    int shift = 0;
    if (tid == 0) {
#pragma unroll
        for (int i = 0; i < K; ++i)
#pragma unroll
            for (int j = 0; j < K; ++j) P[i][j] = (i == j) ? cst[136 + i] : 0.0f;
    } else {
        float4 x0 = xv[0];
        float e[K];
#pragma unroll
        for (int j = 0; j < K; ++j) {
            float em = ca[j];
            em = fmaf(fmaf(cc[j][0], x0.x, cb[j][0]), x0.x, em);
            em = fmaf(fmaf(cc[j][1], x0.y, cb[j][1]), x0.y, em);
            em = fmaf(fmaf(cc[j][2], x0.z, cb[j][2]), x0.z, em);
            em = fmaf(fmaf(cc[j][3], x0.w, cb[j][3]), x0.w, em);
            e[j] = exp2f(em);
        }
#pragma unroll
        for (int i = 0; i < K; ++i)
#pragma unroll
            for (int j = 0; j < K; ++j) P[i][j] = Tr[i][j] * e[j];
    }

    // scan: P <- (P*Tr) .col e_t ; pow2 renorm every 2nd step folded into next e
    float fcarry = 0.0f;
    int icarry = 0;
    float4 xnext = xv[1];
#pragma unroll 1
    for (int t = 1; t < CHUNK; ++t) {
        float4 xt = xnext;
        int tn = (t + 1 < CHUNK) ? (t + 1) : t;
        xnext = xv[tn];
        float e[K];
#pragma unroll
        for (int j = 0; j < K; ++j) {
            float em = ca[j];
            em = fmaf(fmaf(cc[j][0], xt.x, cb[j][0]), xt.x, em);
            em = fmaf(fmaf(cc[j][1], xt.y, cb[j][1]), xt.y, em);
            em = fmaf(fmaf(cc[j][2], xt.z, cb[j][2]), xt.z, em);
            em = fmaf(fmaf(cc[j][3], xt.w, cb[j][3]), xt.w, em);
            e[j] = exp2f(em + fcarry);
        }
        shift -= icarry;
#pragma unroll
        for (int i = 0; i < K; ++i) {
            float q[K];
#pragma unroll
            for (int j = 0; j < K; ++j) q[j] = P[i][0] * Tr[0][j];
#pragma unroll
            for (int k = 1; k < K; ++k)
#pragma unroll
                for (int j = 0; j < K; ++j) q[j] = fmaf(P[i][k], Tr[k][j], q[j]);
#pragma unroll
            for (int j = 0; j < K; ++j) P[i][j] = q[j] * e[j];
        }
        if ((t & 1) == 0) {
            float mx = 0.f;
#pragma unroll
            for (int i = 0; i < K; ++i)
#pragma unroll
                for (int j = 0; j < K; ++j) mx = fmaxf(mx, P[i][j]);
            int ex = (__float_as_int(mx) >> 23) & 255;
            icarry = 127 - ex;
            fcarry = (float)icarry;
        } else {
            icarry = 0;
            fcarry = 0.0f;
        }
    }
    renorm_mat(P, shift);

    hybrid_tree(P, shift, lm, lsh);

    if (threadIdx.x == 0) {
        float4* o4 = reinterpret_cast<float4*>(bp + (size_t)blockIdx.x * 64);
        const float4* l4 = reinterpret_cast<const float4*>(lm);
#pragma unroll
        for (int q = 0; q < 16; ++q) o4[q] = l4[q];
        bs[blockIdx.x] = lsh[0];
    }
}

// 256-thread final: 4 serial combines per thread, then the hybrid tree
__global__ void hmm_final(const float* __restrict__ bp,
                          const int* __restrict__ bs,
                          float* __restrict__ out) {
    __shared__ float lm[128 * MSTRIDE];
    __shared__ int lsh[128];
    const int t = threadIdx.x;
    const int base = t * 4;

    float P[K][K];
    {
        const float4* p4 = reinterpret_cast<const float4*>(bp + (size_t)base * 64);
        float4* dst = reinterpret_cast<float4*>(&P[0][0]);
#pragma unroll
        for (int q = 0; q < 16; ++q) dst[q] = p4[q];
    }
    int shift = bs[base];
#pragma unroll 1
    for (int r = 1; r < 4; ++r) {
        const float* Rp = bp + (size_t)(base + r) * 64;
        float C[K][K];
        combine_stream(&P[0][0], Rp, C);
        shift += bs[base + r];
        renorm_mat(C, shift);
#pragma unroll
        for (int i = 0; i < K; ++i)
#pragma unroll
            for (int j = 0; j < K; ++j) P[i][j] = C[i][j];
    }

    hybrid_tree(P, shift, lm, lsh);

    if (t == 0) {
        double s = 0.0;
#pragma unroll
        for (int i = 0; i < K; ++i)
#pragma unroll
            for (int j = 0; j < K; ++j) s += (double)lm[i * 8 + j];
        out[0] = (float)(log(s) + (double)lsh[0] * 0.69314718055994530942);
    }
}

extern "C" void kernel_launch(void* const* d_in, const int* in_sizes, int n_in,
                              void* d_out, int out_size, void* d_ws, size_t ws_size,
                              hipStream_t stream) {
    (void)in_sizes; (void)n_in; (void)out_size; (void)ws_size;
    const float* x  = (const float*)d_in[0];
    const float* ut = (const float*)d_in[1];
    const float* up = (const float*)d_in[2];
    const float* mn = (const float*)d_in[3];
    const float* ls = (const float*)d_in[4];
    float* ws  = (float*)d_ws;
    float* out = (float*)d_out;
    float* bp  = ws + 256;
    int* bs    = (int*)(ws + 256 + (size_t)NBLK * 64);

    hmm_setup<<<1, 64, 0, stream>>>(x, ut, up, mn, ls, ws);
    hmm_main<<<NBLK, TPB, 0, stream>>>(x, ws, bp, bs);
    hmm_final<<<1, TPB, 0, stream>>>(bp, bs, out);
}